// Round 8
// baseline (331.617 us; speedup 1.0000x reference)
//
#include <hip/hip_runtime.h>
#include <hip/hip_bf16.h>

namespace {

constexpr int E  = 64;
constexpr int C  = 64;
constexpr int D  = 1024;
constexpr int DF = 2048;
constexpr int BK = 128;   // K per tile: 128 f32 = 512 B contiguous per row

using u16    = unsigned short;
using f32x4  = __attribute__((ext_vector_type(4))) float;
using short8 = __attribute__((ext_vector_type(8))) short;

__device__ __forceinline__ u16 f2bf(float f) {
  union { __hip_bfloat16 h; u16 u; } v;
  v.h = __float2bfloat16(f);
  return v.u;
}

__device__ __forceinline__ short8 cvt8(const f32x4& lo, const f32x4& hi) {
  short8 r;
#pragma unroll
  for (int i = 0; i < 4; ++i) {
    r[i]     = (short)f2bf(lo[i]);
    r[4 + i] = (short)f2bf(hi[i]);
  }
  return r;
}

__device__ __forceinline__ void gl_lds16(const void* g, void* l) {
  __builtin_amdgcn_global_load_lds(
      (const __attribute__((address_space(1))) unsigned*)g,
      (__attribute__((address_space(3))) unsigned*)l, 16, 0, 0);
}
__device__ __forceinline__ void gl_lds16_nt(const void* g, void* l) {
  __builtin_amdgcn_global_load_lds(
      (const __attribute__((address_space(1))) unsigned*)g,
      (__attribute__((address_space(3))) unsigned*)l, 16, 0, 2);
}

// fp32 region, 512B rows (32 granules), swizzle: logical granule g lives at
// physical g ^ (row & 31). Returns bf16 frag of logical granules (g, g+1).
__device__ __forceinline__ short8 rd_f32(const char* region, int row, int g) {
  const int x = row & 31;
  f32x4 lo = *reinterpret_cast<const f32x4*>(region + row * 512 + ((g    ) ^ x) * 16);
  f32x4 hi = *reinterpret_cast<const f32x4*>(region + row * 512 + ((g + 1) ^ x) * 16);
  return cvt8(lo, hi);
}

// ---------------- Stage 1: H = silu(X*Wg^T) * (X*Wu^T), bf16 out -----------
// BN=64, BK=128, two sequential K-passes (G then U) over a shared 2-buffer
// ring. Pure-LDS compute loop (FIFO-vmcnt discipline).
__global__ __launch_bounds__(256, 1) void ffn_stage1(
    const float* __restrict__ X, const float* __restrict__ Wg,
    const float* __restrict__ Wu, u16* __restrict__ H) {
  const int b   = blockIdx.x;          // 0..2047
  const int xcd = b & 7;
  const int j   = b >> 3;              // 0..255
  const int e   = xcd + 8 * (j >> 5);  // 32 tiles/expert, one XCD per expert
  const int n0  = (j & 31) * 64;

  const int tid  = threadIdx.x;
  const int lane = tid & 63;
  const int wv   = tid >> 6;           // 0..3, owns W rows wv*16..+16
  const int rl   = lane & 15;
  const int q    = lane >> 4;

  // buffer: W 32KB | X 32KB = 64KB; x2 = 128KB -> 1 block/CU
  __shared__ __align__(16) char lds[2][65536];
  constexpr int OXL = 32768;

  const float* xbase = X  + (size_t)(e * C) * D;
  const float* gbase = Wg + ((size_t)e * DF + n0) * D;
  const float* ubase = Wu + ((size_t)e * DF + n0) * D;

  // one tile: exactly 16 global_load_lds per thread-group member
  auto STAGE = [&](char* lb, const float* wb, int kt) {
#pragma unroll
    for (int i = 0; i < 8; ++i) {
      const int o   = tid + i * 256;   // granule 0..2047
      const int row = o >> 5;          // 64 rows x 512B
      const int gc  = (o & 31) ^ (row & 31);
      const size_t off = (size_t)row * D + (size_t)kt * BK + gc * 4;
      gl_lds16_nt(wb + off, lb + o * 16);        // weights: streaming, NT
      gl_lds16(xbase + off, lb + OXL + o * 16);  // X: L2-reused, normal
    }
  };

  const f32x4 zero = {0.f, 0.f, 0.f, 0.f};
  f32x4 accg[4], accu[4];
#pragma unroll
  for (int mf = 0; mf < 4; ++mf) { accg[mf] = zero; accu[mf] = zero; }

  auto COMPUTE = [&](const char* lb, f32x4 (&acc)[4]) {
#pragma unroll
    for (int ks = 0; ks < 4; ++ks) {   // four K=32 slices of the K=128 tile
      const int kb = ks * 8 + q * 2;   // granule base of this lane's 32B slice
      short8 bfr = rd_f32(lb, wv * 16 + rl, kb);
#pragma unroll
      for (int mf = 0; mf < 4; ++mf) {
        short8 a = rd_f32(lb + OXL, mf * 16 + rl, kb);
        acc[mf] = __builtin_amdgcn_mfma_f32_16x16x32_bf16(a, bfr, acc[mf], 0, 0, 0);
      }
    }
  };

  constexpr int NKP = D / BK;          // 8 tiles per pass
  const int ph = (b * 3) & (NKP - 1);  // per-block K-phase stagger
  auto KT = [&](int t) { return ((t & (NKP - 1)) + ph) & (NKP - 1); };

  STAGE(lds[0], gbase, KT(0));
  STAGE(lds[1], gbase, KT(1));         // 32 outstanding

  for (int s = 0; s < 2 * NKP; ++s) {  // s<8: G pass, s>=8: U pass
    if (s < 2 * NKP - 1) {
      asm volatile("s_waitcnt vmcnt(16)" ::: "memory");  // tile s resident
    } else {
      asm volatile("s_waitcnt vmcnt(0)" ::: "memory");
    }
    __builtin_amdgcn_s_barrier();
    __builtin_amdgcn_sched_barrier(0);
    if (s < NKP) COMPUTE(lds[s & 1], accg);
    else         COMPUTE(lds[s & 1], accu);
    __builtin_amdgcn_sched_barrier(0);
    __builtin_amdgcn_s_barrier();      // all waves done with buffer s&1
    if (s + 2 < 2 * NKP) {
      const float* wsrc = (s + 2 < NKP) ? gbase : ubase;
      STAGE(lds[s & 1], wsrc, KT(s + 2));
    }
  }

  // epilogue: silu(g)*u -> bf16. C/D layout: col=lane&15, row=(lane>>4)*4+reg
#pragma unroll
  for (int mf = 0; mf < 4; ++mf)
#pragma unroll
    for (int r = 0; r < 4; ++r) {
      float gv = accg[mf][r];
      float uv = accu[mf][r];
      float h  = (gv / (1.f + __expf(-gv))) * uv;
      int c = mf * 16 + q * 4 + r;
      int f = n0 + wv * 16 + rl;
      H[((size_t)(e * C) + c) * DF + f] = f2bf(h);
    }
}

// ---------------- Stage 2: out = H * Wd^T (fp32 out) -----------------------
// BN=64, BK=128, single pass, same skeleton.
__global__ __launch_bounds__(256, 1) void ffn_stage2(
    const u16* __restrict__ H, const float* __restrict__ Wd,
    float* __restrict__ out) {
  const int b   = blockIdx.x;          // 0..1023
  const int xcd = b & 7;
  const int j   = b >> 3;              // 0..127
  const int e   = xcd + 8 * (j >> 4);  // same XCD that produced H[e]
  const int n0  = (j & 15) * 64;

  const int tid  = threadIdx.x;
  const int lane = tid & 63;
  const int wv   = tid >> 6;
  const int rl   = lane & 15;
  const int q    = lane >> 4;

  // buffer: Wd 32KB | H 16KB = 48KB; x2 = 96KB -> 1 block/CU
  __shared__ __align__(16) char lds[2][49152];
  constexpr int OHL = 32768;

  const u16*   hbase = H  + (size_t)(e * C) * DF;
  const float* wbase = Wd + ((size_t)e * D + n0) * DF;

  // one tile: 8 Wd + 4 H = 12 global_load_lds per thread
  auto STAGE = [&](char* lb, int kt) {
#pragma unroll
    for (int i = 0; i < 8; ++i) {      // Wd: 64 rows x 512B
      const int o   = tid + i * 256;
      const int row = o >> 5;
      const int gc  = (o & 31) ^ (row & 31);
      gl_lds16_nt(wbase + (size_t)row * DF + (size_t)kt * BK + gc * 4, lb + o * 16);
    }
#pragma unroll
    for (int i = 0; i < 4; ++i) {      // H bf16: 64 rows x 256B (16 granules)
      const int o   = tid + i * 256;
      const int row = o >> 4;
      const int gc  = (o & 15) ^ (row & 15);
      gl_lds16(hbase + (size_t)row * DF + (size_t)kt * BK + gc * 8,
               lb + OHL + o * 16);
    }
  };

  const f32x4 zero = {0.f, 0.f, 0.f, 0.f};
  f32x4 acc[4];
#pragma unroll
  for (int mf = 0; mf < 4; ++mf) acc[mf] = zero;

  auto COMPUTE = [&](const char* lb) {
#pragma unroll
    for (int ks = 0; ks < 4; ++ks) {
      short8 bfr = rd_f32(lb, wv * 16 + rl, ks * 8 + q * 2);
#pragma unroll
      for (int mf = 0; mf < 4; ++mf) {
        const int r = mf * 16 + rl;    // H row, 256B rows, swz ^(row&15)
        short8 a = *reinterpret_cast<const short8*>(
            lb + OHL + r * 256 + (((ks * 4 + q) ^ (r & 15)) * 16));
        acc[mf] = __builtin_amdgcn_mfma_f32_16x16x32_bf16(a, bfr, acc[mf], 0, 0, 0);
      }
    }
  };

  constexpr int NK = DF / BK;          // 16
  const int ph = (b * 7) & (NK - 1);
  auto KT = [&](int t) { return ((t & (NK - 1)) + ph) & (NK - 1); };

  STAGE(lds[0], KT(0));
  STAGE(lds[1], KT(1));                // 24 outstanding

  for (int kt = 0; kt < NK; ++kt) {
    if (kt < NK - 1) {
      asm volatile("s_waitcnt vmcnt(12)" ::: "memory");
    } else {
      asm volatile("s_waitcnt vmcnt(0)" ::: "memory");
    }
    __builtin_amdgcn_s_barrier();
    __builtin_amdgcn_sched_barrier(0);
    COMPUTE(lds[kt & 1]);
    __builtin_amdgcn_sched_barrier(0);
    __builtin_amdgcn_s_barrier();
    if (kt + 2 < NK) STAGE(lds[kt & 1], KT(kt + 2));
  }

#pragma unroll
  for (int mf = 0; mf < 4; ++mf)
#pragma unroll
    for (int r = 0; r < 4; ++r) {
      int c = mf * 16 + q * 4 + r;
      int d = n0 + wv * 16 + rl;
      out[((size_t)(e * C) + c) * D + d] = acc[mf][r];
    }
}

}  // namespace

extern "C" void kernel_launch(void* const* d_in, const int* in_sizes, int n_in,
                              void* d_out, int out_size, void* d_ws, size_t ws_size,
                              hipStream_t stream) {
  const float* X  = (const float*)d_in[0];
  const float* Wg = (const float*)d_in[1];
  const float* Wu = (const float*)d_in[2];
  const float* Wd = (const float*)d_in[3];
  float* out = (float*)d_out;
  u16* H = (u16*)d_ws;  // E*C*DF bf16 = 16.8 MB scratch

  ffn_stage1<<<dim3(E * (DF / 64)), dim3(256), 0, stream>>>(X, Wg, Wu, H);
  ffn_stage2<<<dim3(E * (D / 64)), dim3(256), 0, stream>>>(H, Wd, out);
}

// Round 9
// 276.115 us; speedup vs baseline: 1.2010x; 1.2010x over previous
//
#include <hip/hip_runtime.h>
#include <hip/hip_bf16.h>

namespace {

constexpr int E  = 64;
constexpr int C  = 64;
constexpr int D  = 1024;
constexpr int DF = 2048;
constexpr int BK = 32;    // K per step (32 f32 = 128 B rows in LDS)

using u16    = unsigned short;
using f32x4  = __attribute__((ext_vector_type(4))) float;
using short8 = __attribute__((ext_vector_type(8))) short;

__device__ __forceinline__ u16 f2bf(float f) {
  union { __hip_bfloat16 h; u16 u; } v;
  v.h = __float2bfloat16(f);  // RNE; compiler emits HW cvt
  return v.u;
}

__device__ __forceinline__ short8 cvt8(const f32x4& lo, const f32x4& hi) {
  short8 r;
#pragma unroll
  for (int i = 0; i < 4; ++i) {
    r[i]     = (short)f2bf(lo[i]);
    r[4 + i] = (short)f2bf(hi[i]);
  }
  return r;
}

// async 16B global -> LDS (linear dest: wave-uniform base + lane*16)
__device__ __forceinline__ void gl_lds16(const void* g, void* l) {
  __builtin_amdgcn_global_load_lds(
      (const __attribute__((address_space(1))) unsigned*)g,
      (__attribute__((address_space(3))) unsigned*)l, 16, 0, 0);
}
// same, non-temporal (NT cpol bit): streaming weights, evict-first in L2/L3
__device__ __forceinline__ void gl_lds16_nt(const void* g, void* l) {
  __builtin_amdgcn_global_load_lds(
      (const __attribute__((address_space(1))) unsigned*)g,
      (__attribute__((address_space(3))) unsigned*)l, 16, 0, 2);
}

// read one bf16 fragment (8 f32 -> short8) from a 128B-row fp32 LDS region,
// XOR-swizzled: 16B-granule ^ (row & 7)  (matches the pre-swizzled source)
__device__ __forceinline__ short8 rd_frag_f32(const char* region, int r, int q) {
  const int s  = (r & 7) << 4;
  const int b0 = r * 128 + ((q * 32) ^ s);
  const int b1 = r * 128 + ((q * 32 + 16) ^ s);
  f32x4 lo = *reinterpret_cast<const f32x4*>(region + b0);
  f32x4 hi = *reinterpret_cast<const f32x4*>(region + b1);
  return cvt8(lo, hi);
}

// ---------------- Stage 1: H = silu(X*Wg^T) * (X*Wu^T), bf16 out -----------
__global__ __launch_bounds__(256, 2) void ffn_stage1(
    const float* __restrict__ X, const float* __restrict__ Wg,
    const float* __restrict__ Wu, u16* __restrict__ H) {
  const int b   = blockIdx.x;          // 0..1023
  const int xcd = b & 7;
  const int j   = b >> 3;
  const int e   = xcd + 8 * (j >> 4);  // all 16 tiles of expert e on one XCD
  const int n0  = (j & 15) * 128;

  const int tid  = threadIdx.x;
  const int lane = tid & 63;
  const int wv   = tid >> 6;
  const int rl   = lane & 15;
  const int q    = lane >> 4;

  // per buffer: X 8KB | Wg 16KB | Wu 16KB = 40KB; x2 = 80KB -> 2 blocks/CU
  __shared__ __align__(16) char lds[2][40960];
  constexpr int OX = 0, OG = 8192, OU = 24576;

  const float* xbase = X  + (size_t)(e * C) * D;
  const float* gbase = Wg + ((size_t)e * DF + n0) * D;
  const float* ubase = Wu + ((size_t)e * DF + n0) * D;

  // one K-tile: exactly 10 global_load_lds per wave (vmcnt bookkeeping!)
  auto STAGE = [&](char* lb, int kt) {
#pragma unroll
    for (int i = 0; i < 2; ++i) {  // X: 64 rows x 128B (L2-reused: normal)
      const int o   = tid + i * 256;
      const int row = o >> 3;
      const int gc  = (o & 7) ^ (row & 7);
      gl_lds16(xbase + (size_t)row * D + (size_t)kt * BK + gc * 4, lb + OX + o * 16);
    }
#pragma unroll
    for (int i = 0; i < 4; ++i) {  // Wg/Wu: 128 rows x 128B each (stream: NT)
      const int o   = tid + i * 256;
      const int row = o >> 3;
      const int gc  = (o & 7) ^ (row & 7);
      const size_t goff = (size_t)row * D + (size_t)kt * BK + gc * 4;
      gl_lds16_nt(gbase + goff, lb + OG + o * 16);
      gl_lds16_nt(ubase + goff, lb + OU + o * 16);
    }
  };

  const f32x4 zero = {0.f, 0.f, 0.f, 0.f};
  f32x4 accg[4][2], accu[4][2];
#pragma unroll
  for (int mf = 0; mf < 4; ++mf)
#pragma unroll
    for (int nf = 0; nf < 2; ++nf) { accg[mf][nf] = zero; accu[mf][nf] = zero; }

  auto COMPUTE = [&](const char* lb) {
    short8 a[4], g[2], u[2];
#pragma unroll
    for (int mf = 0; mf < 4; ++mf)
      a[mf] = rd_frag_f32(lb + OX, mf * 16 + rl, q);
#pragma unroll
    for (int nf = 0; nf < 2; ++nf) {
      const int r = wv * 32 + nf * 16 + rl;
      g[nf] = rd_frag_f32(lb + OG, r, q);
      u[nf] = rd_frag_f32(lb + OU, r, q);
    }
#pragma unroll
    for (int mf = 0; mf < 4; ++mf)
#pragma unroll
      for (int nf = 0; nf < 2; ++nf) {
        accg[mf][nf] = __builtin_amdgcn_mfma_f32_16x16x32_bf16(a[mf], g[nf], accg[mf][nf], 0, 0, 0);
        accu[mf][nf] = __builtin_amdgcn_mfma_f32_16x16x32_bf16(a[mf], u[nf], accu[mf][nf], 0, 0, 0);
      }
  };

  constexpr int NK = D / BK;  // 32
  // per-block K-phase stagger: decorrelate the chip-wide DRAM sweep.
  // fp32 MFMA accumulation order is irrelevant at bf16 tolerance.
  const int ph = (b * 11) & (NK - 1);
  auto KT = [&](int s) { return (s + ph) & (NK - 1); };

  STAGE(lds[0], KT(0));
  STAGE(lds[1], KT(1));       // 20 outstanding

  for (int kt = 0; kt < NK - 1; ++kt) {
    asm volatile("s_waitcnt vmcnt(10)" ::: "memory");  // tile kt resident
    __builtin_amdgcn_s_barrier();
    __builtin_amdgcn_sched_barrier(0);
    COMPUTE(lds[kt & 1]);
    __builtin_amdgcn_sched_barrier(0);
    __builtin_amdgcn_s_barrier();            // all waves done reading buf kt&1
    if (kt + 2 < NK) STAGE(lds[kt & 1], KT(kt + 2));
  }
  asm volatile("s_waitcnt vmcnt(0)" ::: "memory");
  __builtin_amdgcn_s_barrier();
  __builtin_amdgcn_sched_barrier(0);
  COMPUTE(lds[(NK - 1) & 1]);

  // epilogue: silu(g)*u -> bf16. C/D layout: col=lane&15, row=(lane>>4)*4+reg
#pragma unroll
  for (int mf = 0; mf < 4; ++mf)
#pragma unroll
    for (int nf = 0; nf < 2; ++nf)
#pragma unroll
      for (int r = 0; r < 4; ++r) {
        float gv = accg[mf][nf][r];
        float uv = accu[mf][nf][r];
        float h  = (gv / (1.f + __expf(-gv))) * uv;
        int c = mf * 16 + (lane >> 4) * 4 + r;
        int f = n0 + wv * 32 + nf * 16 + rl;
        H[((size_t)(e * C) + c) * DF + f] = f2bf(h);
      }
}

// ---------------- Stage 2: out = H * Wd^T (fp32 out) -----------------------
__global__ __launch_bounds__(256, 4) void ffn_stage2(
    const u16* __restrict__ H, const float* __restrict__ Wd,
    float* __restrict__ out) {
  const int b   = blockIdx.x;          // 0..511
  const int xcd = b & 7;
  const int j   = b >> 3;
  const int e   = xcd + 8 * (j >> 3);  // same XCD that produced H[e]
  const int n0  = (j & 7) * 128;

  const int tid  = threadIdx.x;
  const int lane = tid & 63;
  const int wv   = tid >> 6;
  const int rl   = lane & 15;
  const int q    = lane >> 4;

  // per buffer: H 4KB | Wd 16KB = 20KB; x2 = 40KB -> 4 blocks/CU
  __shared__ __align__(16) char lds[2][20480];
  constexpr int OH = 0, OW = 4096;

  const u16*   hbase = H  + (size_t)(e * C) * DF;
  const float* wbase = Wd + ((size_t)e * D + n0) * DF;

  // one K-tile: exactly 5 global_load_lds per wave
  auto STAGE = [&](char* lb, int kt) {
    {  // H: 64 rows x 64B (32 bf16), swz granule ^ ((row>>1)&3). L2-reused.
      const int row = tid >> 2;
      const int gc  = (tid & 3) ^ ((row >> 1) & 3);
      gl_lds16(hbase + (size_t)row * DF + (size_t)kt * BK + gc * 8, lb + OH + tid * 16);
    }
#pragma unroll
    for (int i = 0; i < 4; ++i) {  // Wd: 128 rows x 128B. Stream: NT.
      const int o   = tid + i * 256;
      const int row = o >> 3;
      const int gc  = (o & 7) ^ (row & 7);
      gl_lds16_nt(wbase + (size_t)row * DF + (size_t)kt * BK + gc * 4, lb + OW + o * 16);
    }
  };

  const f32x4 zero = {0.f, 0.f, 0.f, 0.f};
  f32x4 acc[4][2];
#pragma unroll
  for (int mf = 0; mf < 4; ++mf)
#pragma unroll
    for (int nf = 0; nf < 2; ++nf) acc[mf][nf] = zero;

  auto COMPUTE = [&](const char* lb) {
    short8 a[4], bfr[2];
#pragma unroll
    for (int mf = 0; mf < 4; ++mf) {  // bf16 H frags, swizzled read
      const int r  = mf * 16 + rl;
      const int gp = q ^ ((r >> 1) & 3);
      a[mf] = *reinterpret_cast<const short8*>(lb + OH + r * 64 + gp * 16);
    }
#pragma unroll
    for (int nf = 0; nf < 2; ++nf)
      bfr[nf] = rd_frag_f32(lb + OW, wv * 32 + nf * 16 + rl, q);
#pragma unroll
    for (int mf = 0; mf < 4; ++mf)
#pragma unroll
      for (int nf = 0; nf < 2; ++nf)
        acc[mf][nf] = __builtin_amdgcn_mfma_f32_16x16x32_bf16(a[mf], bfr[nf], acc[mf][nf], 0, 0, 0);
  };

  constexpr int NK = DF / BK;  // 64
  const int ph = (b * 11) & (NK - 1);
  auto KT = [&](int s) { return (s + ph) & (NK - 1); };

  STAGE(lds[0], KT(0));
  STAGE(lds[1], KT(1));        // 10 outstanding

  for (int kt = 0; kt < NK - 1; ++kt) {
    asm volatile("s_waitcnt vmcnt(5)" ::: "memory");
    __builtin_amdgcn_s_barrier();
    __builtin_amdgcn_sched_barrier(0);
    COMPUTE(lds[kt & 1]);
    __builtin_amdgcn_sched_barrier(0);
    __builtin_amdgcn_s_barrier();
    if (kt + 2 < NK) STAGE(lds[kt & 1], KT(kt + 2));
  }
  asm volatile("s_waitcnt vmcnt(0)" ::: "memory");
  __builtin_amdgcn_s_barrier();
  __builtin_amdgcn_sched_barrier(0);
  COMPUTE(lds[(NK - 1) & 1]);

#pragma unroll
  for (int mf = 0; mf < 4; ++mf)
#pragma unroll
    for (int nf = 0; nf < 2; ++nf)
#pragma unroll
      for (int r = 0; r < 4; ++r) {
        int c = mf * 16 + (lane >> 4) * 4 + r;
        int d = n0 + wv * 32 + nf * 16 + rl;
        out[((size_t)(e * C) + c) * D + d] = acc[mf][nf][r];
      }
}

}  // namespace

extern "C" void kernel_launch(void* const* d_in, const int* in_sizes, int n_in,
                              void* d_out, int out_size, void* d_ws, size_t ws_size,
                              hipStream_t stream) {
  const float* X  = (const float*)d_in[0];
  const float* Wg = (const float*)d_in[1];
  const float* Wu = (const float*)d_in[2];
  const float* Wd = (const float*)d_in[3];
  float* out = (float*)d_out;
  u16* H = (u16*)d_ws;  // E*C*DF bf16 = 16.8 MB scratch

  ffn_stage1<<<dim3(E * (DF / 128)), dim3(256), 0, stream>>>(X, Wg, Wu, H);
  ffn_stage2<<<dim3(E * (D / 128)), dim3(256), 0, stream>>>(H, Wd, out);
}